// Round 8
// baseline (53.105 us; speedup 1.0000x reference)
//
#include <hip/hip_runtime.h>

#define IMG   512
#define NCLS  256
#define DIM   1024
#define HPW   32
#define TPB   8            // tokens per block (rows 8..15 of MFMA tile are zero)
#define NT2   512          // 8 waves; wave owns 128 dims

typedef short bf16x8 __attribute__((ext_vector_type(8)));
typedef float f32x4  __attribute__((ext_vector_type(4)));

__device__ inline ushort bf16rne(float v) {
    unsigned u = __float_as_uint(v);
    return (ushort)((u + 0x7fffu + ((u >> 16) & 1u)) >> 16);
}

// ---------- K1: table f32 [256 cls][1024 dim] -> Tt bf16 [1024 dim][256 cls] ----------
__global__ __launch_bounds__(256)
void transpose_table(const float* __restrict__ table, ushort* __restrict__ Tt)
{
    __shared__ ushort tile[64][66];
    const int c0 = blockIdx.x * 64;
    const int d0 = blockIdx.y * 64;
    const int t  = threadIdx.x;

    #pragma unroll
    for (int it = 0; it < 16; ++it) {
        const int idx = it * 256 + t;
        const int cl  = idx >> 6, dl = idx & 63;          // coalesced along dims
        tile[dl][cl] = bf16rne(table[(size_t)(c0 + cl) * DIM + d0 + dl]);
    }
    __syncthreads();
    #pragma unroll
    for (int it = 0; it < 16; ++it) {
        const int idx = it * 256 + t;
        const int dl  = idx >> 6, cl = idx & 63;          // coalesced along classes
        Tt[(size_t)(d0 + dl) * NCLS + c0 + cl] = tile[dl][cl];
    }
}

// ---------- K2: hist -> MFMA (8 tok x 1024 dim x 256 cls) -> pos -> LN -> out ----------
__global__ __launch_bounds__(NT2, 4)   // cap 128 VGPR, 2 blocks/CU
void gemm8(const int* __restrict__ smap, const ushort* __restrict__ Tt,
           const float* __restrict__ gamma, const float* __restrict__ beta,
           float* __restrict__ out)
{
    __shared__ unsigned cnt[TPB * NCLS];      // 8 KB
    __shared__ ushort   cntb[16][264];        // rows 8..15 stay zero; stride 528 B
    __shared__ float    red[8][2][4][2];      // [wave][g][i][{s,s2}]

    const int t    = threadIdx.x;
    const int lane = t & 63;
    const int w    = t >> 6;                  // 8 waves; wave owns dims [w*128, w*128+128)
    const int c    = lane & 15;
    const int g    = lane >> 4;

    const int tok0 = blockIdx.x * TPB;
    const int b    = tok0 >> 10;
    const int ph   = (tok0 >> 5) & 31;
    const int pw0  = tok0 & 31;

    // ---- zero ----
    #pragma unroll
    for (int i = t; i < TPB * NCLS; i += NT2) cnt[i] = 0u;
    #pragma unroll
    for (int i = t; i < 16 * 264; i += NT2) (&cntb[0][0])[i] = 0;
    __syncthreads();

    // ---- histogram: 16 rows x 128 cols (8 patches), int4 per thread ----
    {
        const int row = t >> 5;               // 0..15
        const int col = (t & 31) * 4;         // 0..124
        const int4 q = *reinterpret_cast<const int4*>(
            smap + ((size_t)b * IMG + (size_t)(ph * 16 + row)) * IMG + pw0 * 16 + col);
        unsigned* hp = &cnt[(col >> 4) * NCLS];
        atomicAdd(&hp[min(max(q.x, 0), NCLS - 1)], 1u);
        atomicAdd(&hp[min(max(q.y, 0), NCLS - 1)], 1u);
        atomicAdd(&hp[min(max(q.z, 0), NCLS - 1)], 1u);
        atomicAdd(&hp[min(max(q.w, 0), NCLS - 1)], 1u);
    }
    __syncthreads();

    // ---- counts -> bf16(count/256), exact (<=8 significant bits) ----
    #pragma unroll
    for (int i = t; i < TPB * NCLS; i += NT2)
        cntb[i >> 8][i & 255] = (ushort)(__float_as_uint((float)cnt[i] * (1.f / 256.f)) >> 16);
    __syncthreads();

    // ---- A fragments (token rows; rows 8..15 zero) ----
    bf16x8 af[8];
    #pragma unroll
    for (int ks = 0; ks < 8; ++ks)
        af[ks] = *reinterpret_cast<const bf16x8*>(&cntb[c][ks * 32 + g * 8]);

    // ---- MFMA K-loop; B straight from Tt (bf16, dwordx4 per fragment) ----
    f32x4 acc[8];
    #pragma unroll
    for (int i = 0; i < 8; ++i) acc[i] = (f32x4){0.f, 0.f, 0.f, 0.f};

    const ushort* bt = Tt + (size_t)(w * 128 + c) * NCLS + g * 8;
    #pragma unroll 1                          // keep B-loads per-ks (no giant hoist)
    for (int ks = 0; ks < 8; ++ks) {
        bf16x8 bfv[8];
        #pragma unroll
        for (int nf = 0; nf < 8; ++nf)
            bfv[nf] = *reinterpret_cast<const bf16x8*>(bt + (size_t)nf * 16 * NCLS + ks * 32);
        #pragma unroll
        for (int nf = 0; nf < 8; ++nf)
            acc[nf] = __builtin_amdgcn_mfma_f32_16x16x32_bf16(af[ks], bfv[nf], acc[nf], 0, 0, 0);
    }

    // ---- pos-embed + LN partials.  d = w*128 + nf*16 + c; D row r=g*4+i ----
    const int quad   = w >> 1;                // d>>8, wave-constant
    const int cosSel = quad & 1;
    float ls[4]  = {0, 0, 0, 0};
    float ls2[4] = {0, 0, 0, 0};

    #pragma unroll
    for (int nf = 0; nf < 8; ++nf) {
        const int dlow = (w & 1) * 128 + nf * 16 + c;     // d & 255
        const float omega = exp2f((float)dlow * (-13.287712379549449f / 256.f));
        if (quad < 2) {                       // h-embed: depends only on ph
            float sv, cv; __sincosf((float)ph * omega, &sv, &cv);
            const float v = cosSel ? cv : sv;
            #pragma unroll
            for (int i = 0; i < 4; ++i) acc[nf][i] += v;
        } else {                              // w-embed: pw = pw0 + g*4 + i
            #pragma unroll
            for (int i = 0; i < 4; ++i) {
                float sv, cv; __sincosf((float)(pw0 + g * 4 + i) * omega, &sv, &cv);
                acc[nf][i] += cosSel ? cv : sv;
            }
        }
        #pragma unroll
        for (int i = 0; i < 4; ++i) { ls[i] += acc[nf][i]; ls2[i] += acc[nf][i] * acc[nf][i]; }
    }

    #pragma unroll
    for (int off = 1; off < 16; off <<= 1) {  // reduce over the 16 c-lanes
        #pragma unroll
        for (int i = 0; i < 4; ++i) {
            ls[i]  += __shfl_xor(ls[i],  off, 64);
            ls2[i] += __shfl_xor(ls2[i], off, 64);
        }
    }
    if (c == 0 && g < 2) {
        #pragma unroll
        for (int i = 0; i < 4; ++i) { red[w][g][i][0] = ls[i]; red[w][g][i][1] = ls2[i]; }
    }
    __syncthreads();

    // ---- finalize LN + store (valid rows r = g*4+i, g<2) ----
    if (g < 2) {
        float mu[4], rs[4];
        #pragma unroll
        for (int i = 0; i < 4; ++i) {
            float S = 0.f, S2 = 0.f;
            #pragma unroll
            for (int ww = 0; ww < 8; ++ww) { S += red[ww][g][i][0]; S2 += red[ww][g][i][1]; }
            mu[i] = S * (1.f / DIM);
            rs[i] = rsqrtf(S2 * (1.f / DIM) - mu[i] * mu[i] + 1e-5f);
        }
        #pragma unroll
        for (int nf = 0; nf < 8; ++nf) {
            const int d = w * 128 + nf * 16 + c;
            const float gv = gamma[d], bv = beta[d];
            #pragma unroll
            for (int i = 0; i < 4; ++i) {
                const int r = g * 4 + i;
                out[(size_t)(tok0 + r) * DIM + d] = (acc[nf][i] - mu[i]) * rs[i] * gv + bv;
            }
        }
    }
}

extern "C" void kernel_launch(void* const* d_in, const int* in_sizes, int n_in,
                              void* d_out, int out_size, void* d_ws, size_t ws_size,
                              hipStream_t stream) {
    const int*   smap  = (const int*)d_in[0];
    const float* table = (const float*)d_in[1];
    const float* gamma = (const float*)d_in[2];
    const float* beta  = (const float*)d_in[3];
    float*       out   = (float*)d_out;
    ushort*      Tt    = (ushort*)d_ws;                  // 512 KB

    const int batches = in_sizes[0] / (IMG * IMG);       // = 2
    const int tokens  = batches * HPW * HPW;             // 2048

    dim3 tgrid(NCLS / 64, DIM / 64);                     // (4, 16)
    transpose_table<<<tgrid, 256, 0, stream>>>(table, Tt);
    gemm8<<<tokens / TPB, NT2, 0, stream>>>(smap, Tt, gamma, beta, out);
}

// Round 9
// 29.608 us; speedup vs baseline: 1.7936x; 1.7936x over previous
//
#include <hip/hip_runtime.h>

#define IMG   512
#define NCLS  256
#define DIM   1024
#define HPW   32
#define TPB   8            // tokens per block (MFMA rows 8..15 zero)
#define NT2   1024         // 16 waves; wave owns 64 dims

typedef short bf16x8 __attribute__((ext_vector_type(8)));
typedef float f32x4  __attribute__((ext_vector_type(4)));

__device__ inline ushort bf16rne(float v) {
    unsigned u = __float_as_uint(v);
    return (ushort)((u + 0x7fffu + ((u >> 16) & 1u)) >> 16);
}

// ---------- K1: table f32 [256 cls][1024 dim] -> Tt bf16 [1024 dim][256 cls] ----------
__global__ __launch_bounds__(256)
void transpose_table(const float* __restrict__ table, ushort* __restrict__ Tt)
{
    __shared__ ushort tile[64][66];
    const int c0 = blockIdx.x * 64;
    const int d0 = blockIdx.y * 64;
    const int t  = threadIdx.x;

    #pragma unroll
    for (int it = 0; it < 16; ++it) {
        const int idx = it * 256 + t;
        const int cl  = idx >> 6, dl = idx & 63;          // coalesced along dims
        tile[dl][cl] = bf16rne(table[(size_t)(c0 + cl) * DIM + d0 + dl]);
    }
    __syncthreads();
    #pragma unroll
    for (int it = 0; it < 16; ++it) {
        const int idx = it * 256 + t;
        const int dl  = idx >> 6, cl = idx & 63;          // coalesced along classes
        Tt[(size_t)(d0 + dl) * NCLS + c0 + cl] = tile[dl][cl];
    }
}

// ---------- K2: hist -> MFMA (8 tok x 1024 dim x 256 cls) -> pos -> LN -> out ----------
__global__ __launch_bounds__(NT2)      // no min-waves arg: natural 128-VGPR cap
void gemm_ln(const int* __restrict__ smap, const ushort* __restrict__ Tt,
             const float* __restrict__ gamma, const float* __restrict__ beta,
             float* __restrict__ out)
{
    __shared__ unsigned cnt[TPB * NCLS];      // 8 KB
    __shared__ ushort   cntb[16][264];        // rows 8..15 stay zero; stride 528 B
    __shared__ float    red[16][2][4][2];     // [wave][g][i][{s,s2}]

    const int t    = threadIdx.x;
    const int lane = t & 63;
    const int w    = t >> 6;                  // 16 waves; wave owns dims [w*64, w*64+64)
    const int c    = lane & 15;
    const int g    = lane >> 4;

    const int tok0 = blockIdx.x * TPB;
    const int b    = tok0 >> 10;
    const int ph   = (tok0 >> 5) & 31;
    const int pw0  = tok0 & 31;

    // ---- zero ----
    for (int i = t; i < TPB * NCLS; i += NT2) cnt[i] = 0u;
    for (int i = t; i < 16 * 264; i += NT2) (&cntb[0][0])[i] = 0;
    __syncthreads();

    // ---- histogram: 8 patches = 16 rows x 128 cols, int2 per thread ----
    {
        const int p   = t * 2;
        const int row = p >> 7;               // 0..15
        const int col = p & 127;
        const int2 q = *reinterpret_cast<const int2*>(
            smap + ((size_t)b * IMG + (size_t)(ph * 16 + row)) * IMG + pw0 * 16 + col);
        unsigned* hp = &cnt[(col >> 4) * NCLS];
        atomicAdd(&hp[min(max(q.x, 0), NCLS - 1)], 1u);
        atomicAdd(&hp[min(max(q.y, 0), NCLS - 1)], 1u);
    }
    __syncthreads();

    // ---- counts -> bf16(count/256), exact (<=8 significant bits) ----
    for (int i = t; i < TPB * NCLS; i += NT2)
        cntb[i >> 8][i & 255] = (ushort)(__float_as_uint((float)cnt[i] * (1.f / 256.f)) >> 16);
    __syncthreads();

    // ---- MFMA K-loop; A re-read from LDS each step (register-lean),
    //      B straight from Tt (bf16 dwordx4), all indices static ----
    f32x4 acc[4];
    #pragma unroll
    for (int i = 0; i < 4; ++i) acc[i] = (f32x4){0.f, 0.f, 0.f, 0.f};

    const ushort* bt = Tt + (size_t)(w * 64 + c) * NCLS + g * 8;
    #pragma unroll 2
    for (int ks = 0; ks < 8; ++ks) {
        const bf16x8 a = *reinterpret_cast<const bf16x8*>(&cntb[c][ks * 32 + g * 8]);
        bf16x8 bfv[4];
        #pragma unroll
        for (int nf = 0; nf < 4; ++nf)
            bfv[nf] = *reinterpret_cast<const bf16x8*>(bt + (size_t)nf * 16 * NCLS + ks * 32);
        #pragma unroll
        for (int nf = 0; nf < 4; ++nf)
            acc[nf] = __builtin_amdgcn_mfma_f32_16x16x32_bf16(a, bfv[nf], acc[nf], 0, 0, 0);
    }

    // ---- pos-embed + LN partials.  d = w*64 + nf*16 + c; D row r = g*4+i ----
    const int quad   = w >> 2;                // d>>8, wave-constant
    const int cosSel = quad & 1;
    float ls[4]  = {0, 0, 0, 0};
    float ls2[4] = {0, 0, 0, 0};

    #pragma unroll
    for (int nf = 0; nf < 4; ++nf) {
        const int dlow = (w & 3) * 64 + nf * 16 + c;      // d & 255
        const float omega = exp2f((float)dlow * (-13.287712379549449f / 256.f));
        if (quad < 2) {                       // h-embed: depends only on ph
            float sv, cv; __sincosf((float)ph * omega, &sv, &cv);
            const float v = cosSel ? cv : sv;
            #pragma unroll
            for (int i = 0; i < 4; ++i) acc[nf][i] += v;
        } else {                              // w-embed: pw = pw0 + g*4 + i (valid g<2)
            #pragma unroll
            for (int i = 0; i < 4; ++i) {
                float sv, cv; __sincosf((float)(pw0 + g * 4 + i) * omega, &sv, &cv);
                acc[nf][i] += cosSel ? cv : sv;
            }
        }
        #pragma unroll
        for (int i = 0; i < 4; ++i) { ls[i] += acc[nf][i]; ls2[i] += acc[nf][i] * acc[nf][i]; }
    }

    #pragma unroll
    for (int off = 1; off < 16; off <<= 1) {  // reduce over the 16 c-lanes (g preserved)
        #pragma unroll
        for (int i = 0; i < 4; ++i) {
            ls[i]  += __shfl_xor(ls[i],  off, 64);
            ls2[i] += __shfl_xor(ls2[i], off, 64);
        }
    }
    if (c == 0 && g < 2) {
        #pragma unroll
        for (int i = 0; i < 4; ++i) { red[w][g][i][0] = ls[i]; red[w][g][i][1] = ls2[i]; }
    }
    __syncthreads();

    // ---- finalize LN + store (valid rows r = g*4+i, g<2) ----
    if (g < 2) {
        float mu[4], rs[4];
        #pragma unroll
        for (int i = 0; i < 4; ++i) {
            float S = 0.f, S2 = 0.f;
            #pragma unroll
            for (int ww = 0; ww < 16; ++ww) { S += red[ww][g][i][0]; S2 += red[ww][g][i][1]; }
            mu[i] = S * (1.f / DIM);
            rs[i] = rsqrtf(S2 * (1.f / DIM) - mu[i] * mu[i] + 1e-5f);
        }
        #pragma unroll
        for (int nf = 0; nf < 4; ++nf) {
            const int d = w * 64 + nf * 16 + c;
            const float gv = gamma[d], bv = beta[d];
            #pragma unroll
            for (int i = 0; i < 4; ++i) {
                const int r = g * 4 + i;
                out[(size_t)(tok0 + r) * DIM + d] = (acc[nf][i] - mu[i]) * rs[i] * gv + bv;
            }
        }
    }
}

extern "C" void kernel_launch(void* const* d_in, const int* in_sizes, int n_in,
                              void* d_out, int out_size, void* d_ws, size_t ws_size,
                              hipStream_t stream) {
    const int*   smap  = (const int*)d_in[0];
    const float* table = (const float*)d_in[1];
    const float* gamma = (const float*)d_in[2];
    const float* beta  = (const float*)d_in[3];
    float*       out   = (float*)d_out;
    ushort*      Tt    = (ushort*)d_ws;                  // 512 KB

    const int batches = in_sizes[0] / (IMG * IMG);       // = 2
    const int tokens  = batches * HPW * HPW;             // 2048

    dim3 tgrid(NCLS / 64, DIM / 64);                     // (4, 16)
    transpose_table<<<tgrid, 256, 0, stream>>>(table, Tt);
    gemm_ln<<<tokens / TPB, NT2, 0, stream>>>(smap, Tt, gamma, beta, out);
}

// Round 10
// 22.016 us; speedup vs baseline: 2.4121x; 1.3448x over previous
//
#include <hip/hip_runtime.h>

#define IMG   512
#define NCLS  256
#define DIM   1024
#define HPW   32
#define TPB   8            // tokens per block (MFMA rows 8..15 zero)
#define NT2   1024         // 16 waves; wave owns 64 dims

typedef short bf16x8 __attribute__((ext_vector_type(8)));
typedef float f32x4  __attribute__((ext_vector_type(4)));

__device__ inline ushort bf16rne(float v) {
    unsigned u = __float_as_uint(v);
    return (ushort)((u + 0x7fffu + ((u >> 16) & 1u)) >> 16);
}

// ---------- K1: pack table f32 [256 cls][1024 dim] into fragment-ordered bf16 ----------
// Tt2 flat (ushorts): [dtile 0..63][ks 0..7][g 0..3][c 0..15][j 0..7]
//   Tt2[dtile*4096 + ks*512 + g*128 + c*8 + j] = bf16(table[ks*32+g*8+j][dtile*16+c])
// K2's wave lane l = g*16+c then reads one contiguous 1 KB chunk per (dtile,ks).
__global__ __launch_bounds__(256)
void pack_table(const float* __restrict__ table, ushort* __restrict__ Tt2)
{
    __shared__ ushort tile[16][264];          // [dim-in-tile][cls], 528 B row stride
    const int dtile = blockIdx.x;
    const int d0    = dtile * 16;
    const int t     = threadIdx.x;            // = class

    // load: thread t reads 16 dims of class t (4x float4, within one row)
    {
        const float* src = table + (size_t)t * DIM + d0;
        #pragma unroll
        for (int q = 0; q < 4; ++q) {
            const float4 v = *reinterpret_cast<const float4*>(src + q * 4);
            tile[q * 4 + 0][t] = bf16rne(v.x);
            tile[q * 4 + 1][t] = bf16rne(v.y);
            tile[q * 4 + 2][t] = bf16rne(v.z);
            tile[q * 4 + 3][t] = bf16rne(v.w);
        }
    }
    __syncthreads();

    // write: thread t owns flat [t*16 .. t*16+16) = dims (c0,c0+1) x classes [cls0,cls0+8)
    const int ks   = t >> 5;
    const int g    = (t >> 3) & 3;
    const int c0   = (t & 7) * 2;
    const int cls0 = ks * 32 + g * 8;
    uint4* dst = reinterpret_cast<uint4*>(Tt2 + (size_t)dtile * 4096 + (size_t)t * 16);
    dst[0] = *reinterpret_cast<const uint4*>(&tile[c0][cls0]);
    dst[1] = *reinterpret_cast<const uint4*>(&tile[c0 + 1][cls0]);
}

// ---------- K2: hist -> MFMA (8 tok x 1024 dim x 256 cls) -> pos -> LN -> out ----------
__global__ __launch_bounds__(NT2)      // no min-waves arg: natural 128-VGPR cap
void gemm_ln(const int* __restrict__ smap, const ushort* __restrict__ Tt2,
             const float* __restrict__ gamma, const float* __restrict__ beta,
             float* __restrict__ out)
{
    __shared__ unsigned cnt[TPB * NCLS];      // 8 KB
    __shared__ ushort   cntb[16][264];        // rows 8..15 stay zero; stride 528 B
    __shared__ float    red[16][2][4][2];     // [wave][g][i][{s,s2}]

    const int t    = threadIdx.x;
    const int lane = t & 63;
    const int w    = t >> 6;                  // 16 waves; wave owns dims [w*64, w*64+64)
    const int c    = lane & 15;
    const int g    = lane >> 4;

    const int tok0 = blockIdx.x * TPB;
    const int b    = tok0 >> 10;
    const int ph   = (tok0 >> 5) & 31;
    const int pw0  = tok0 & 31;

    // ---- zero ----
    for (int i = t; i < TPB * NCLS; i += NT2) cnt[i] = 0u;
    for (int i = t; i < 16 * 264; i += NT2) (&cntb[0][0])[i] = 0;
    __syncthreads();

    // ---- histogram: 8 patches = 16 rows x 128 cols, int2 per thread ----
    {
        const int p   = t * 2;
        const int row = p >> 7;               // 0..15
        const int col = p & 127;
        const int2 q = *reinterpret_cast<const int2*>(
            smap + ((size_t)b * IMG + (size_t)(ph * 16 + row)) * IMG + pw0 * 16 + col);
        unsigned* hp = &cnt[(col >> 4) * NCLS];
        atomicAdd(&hp[min(max(q.x, 0), NCLS - 1)], 1u);
        atomicAdd(&hp[min(max(q.y, 0), NCLS - 1)], 1u);
    }
    __syncthreads();

    // ---- counts -> bf16(count/256), exact (<=8 significant bits) ----
    for (int i = t; i < TPB * NCLS; i += NT2)
        cntb[i >> 8][i & 255] = (ushort)(__float_as_uint((float)cnt[i] * (1.f / 256.f)) >> 16);
    __syncthreads();

    // ---- MFMA K-loop; A from LDS (broadcast b128), B = contiguous 1 KB wave-loads ----
    f32x4 acc[4];
    #pragma unroll
    for (int i = 0; i < 4; ++i) acc[i] = (f32x4){0.f, 0.f, 0.f, 0.f};

    // wave w covers dtiles w*4 .. w*4+3 (nf); lane reads 16 B at lane*16
    const ushort* bt = Tt2 + (size_t)(w * 4) * 4096 + (size_t)lane * 8;
    #pragma unroll 2
    for (int ks = 0; ks < 8; ++ks) {
        const bf16x8 a = *reinterpret_cast<const bf16x8*>(&cntb[c][ks * 32 + g * 8]);
        bf16x8 bfv[4];
        #pragma unroll
        for (int nf = 0; nf < 4; ++nf)
            bfv[nf] = *reinterpret_cast<const bf16x8*>(bt + (size_t)nf * 4096 + ks * 512);
        #pragma unroll
        for (int nf = 0; nf < 4; ++nf)
            acc[nf] = __builtin_amdgcn_mfma_f32_16x16x32_bf16(a, bfv[nf], acc[nf], 0, 0, 0);
    }

    // ---- pos-embed + LN partials.  d = w*64 + nf*16 + c; D row r = g*4+i ----
    const int quad   = w >> 2;                // d>>8, wave-constant
    const int cosSel = quad & 1;
    float ls[4]  = {0, 0, 0, 0};
    float ls2[4] = {0, 0, 0, 0};

    #pragma unroll
    for (int nf = 0; nf < 4; ++nf) {
        const int dlow = (w & 3) * 64 + nf * 16 + c;      // d & 255
        const float omega = exp2f((float)dlow * (-13.287712379549449f / 256.f));
        if (quad < 2) {                       // h-embed: depends only on ph
            float sv, cv; __sincosf((float)ph * omega, &sv, &cv);
            const float v = cosSel ? cv : sv;
            #pragma unroll
            for (int i = 0; i < 4; ++i) acc[nf][i] += v;
        } else {                              // w-embed: pw = pw0 + g*4 + i (valid g<2)
            #pragma unroll
            for (int i = 0; i < 4; ++i) {
                float sv, cv; __sincosf((float)(pw0 + g * 4 + i) * omega, &sv, &cv);
                acc[nf][i] += cosSel ? cv : sv;
            }
        }
        #pragma unroll
        for (int i = 0; i < 4; ++i) { ls[i] += acc[nf][i]; ls2[i] += acc[nf][i] * acc[nf][i]; }
    }

    #pragma unroll
    for (int off = 1; off < 16; off <<= 1) {  // reduce over the 16 c-lanes (g preserved)
        #pragma unroll
        for (int i = 0; i < 4; ++i) {
            ls[i]  += __shfl_xor(ls[i],  off, 64);
            ls2[i] += __shfl_xor(ls2[i], off, 64);
        }
    }
    if (c == 0 && g < 2) {
        #pragma unroll
        for (int i = 0; i < 4; ++i) { red[w][g][i][0] = ls[i]; red[w][g][i][1] = ls2[i]; }
    }
    __syncthreads();

    // ---- finalize LN + store (valid rows r = g*4+i, g<2) ----
    if (g < 2) {
        float mu[4], rs[4];
        #pragma unroll
        for (int i = 0; i < 4; ++i) {
            float S = 0.f, S2 = 0.f;
            #pragma unroll
            for (int ww = 0; ww < 16; ++ww) { S += red[ww][g][i][0]; S2 += red[ww][g][i][1]; }
            mu[i] = S * (1.f / DIM);
            rs[i] = rsqrtf(S2 * (1.f / DIM) - mu[i] * mu[i] + 1e-5f);
        }
        #pragma unroll
        for (int nf = 0; nf < 4; ++nf) {
            const int d = w * 64 + nf * 16 + c;
            const float gv = gamma[d], bv = beta[d];
            #pragma unroll
            for (int i = 0; i < 4; ++i) {
                const int r = g * 4 + i;
                out[(size_t)(tok0 + r) * DIM + d] = (acc[nf][i] - mu[i]) * rs[i] * gv + bv;
            }
        }
    }
}

extern "C" void kernel_launch(void* const* d_in, const int* in_sizes, int n_in,
                              void* d_out, int out_size, void* d_ws, size_t ws_size,
                              hipStream_t stream) {
    const int*   smap  = (const int*)d_in[0];
    const float* table = (const float*)d_in[1];
    const float* gamma = (const float*)d_in[2];
    const float* beta  = (const float*)d_in[3];
    float*       out   = (float*)d_out;
    ushort*      Tt2   = (ushort*)d_ws;                  // 512 KB

    const int batches = in_sizes[0] / (IMG * IMG);       // = 2
    const int tokens  = batches * HPW * HPW;             // 2048

    pack_table<<<DIM / 16, 256, 0, stream>>>(table, Tt2);      // 64 blocks
    gemm_ln<<<tokens / TPB, NT2, 0, stream>>>(smap, Tt2, gamma, beta, out);
}